// Round 11
// baseline (223.028 us; speedup 1.0000x reference)
//
#include <hip/hip_runtime.h>
#include <math.h>

#define BB 2
#define SS 2048
#define DD 1024
#define HH 16
#define HDIM 64

typedef __bf16 bf16_t;
typedef __attribute__((ext_vector_type(8))) __bf16 bf16x8;
typedef __attribute__((ext_vector_type(4))) __bf16 bf16x4;
typedef __attribute__((ext_vector_type(4))) float f32x4;

__device__ inline bf16_t f2bf(float f) {
    unsigned int x; __builtin_memcpy(&x, &f, 4);
    unsigned int r = (x + 0x7FFFu + ((x >> 16) & 1u)) >> 16;  // RNE
    unsigned short us = (unsigned short)r;
    bf16_t b; __builtin_memcpy(&b, &us, 2); return b;
}
__device__ inline unsigned int cvtpk(float a, float b) {  // lo=bf16(a), hi=bf16(b), RNE
    unsigned int r;
    asm("v_cvt_pk_bf16_f32 %0, %1, %2" : "=v"(r) : "v"(a), "v"(b));
    return r;
}
__device__ inline void gload16(const void* g, void* lds_base) {
    __builtin_amdgcn_global_load_lds(
        (const __attribute__((address_space(1))) void*)g,
        (__attribute__((address_space(3))) void*)lds_base, 16, 0, 0);
}

#define SCL 0.18033688f   // (1/sqrt(64)) * log2(e)
#define FM  12.0f

// ---------- prep: dense grid; blocks 0..2047 x-cvt, 2048..2559 pack 4 weights ----------
__global__ __launch_bounds__(256)
void prep_kernel(const float* __restrict__ x, bf16_t* __restrict__ xb,
                 const float* __restrict__ W0, const float* __restrict__ W1,
                 const float* __restrict__ W2, const float* __restrict__ W3,
                 bf16x8* __restrict__ P0, bf16x8* __restrict__ P1,
                 bf16x8* __restrict__ P2, bf16x8* __restrict__ P3) {
    const int bid = blockIdx.x, tid = threadIdx.x;
    if (bid < 2048) {
        const int i = bid * 512 + tid;
        #pragma unroll
        for (int u = 0; u < 2; ++u) {
            const int j = i + u * 256;
            const float4 v = reinterpret_cast<const float4*>(x)[j];
            bf16x4 o;
            o.x = f2bf(v.x); o.y = f2bf(v.y); o.z = f2bf(v.z); o.w = f2bf(v.w);
            reinterpret_cast<bf16x4*>(xb)[j] = o;
        }
    } else {
        const int t = (bid - 2048) * 256 + tid;   // 0..131071
        const int g = t >> 10, n = t & 1023;
        const float* Ws[4] = {W0, W1, W2, W3};
        bf16x8* Pp[4] = {P0, P1, P2, P3};
        #pragma unroll
        for (int m = 0; m < 4; ++m) {
            bf16x8 v;
            #pragma unroll
            for (int j = 0; j < 8; ++j) v[j] = f2bf(Ws[m][(size_t)(g * 8 + j) * DD + n]);
            Pp[m][(size_t)g * DD + n] = v;
        }
    }
}

// ---------- fused QKV GEMM: 128x128 tile, BK=32, 3-buf counted-vmcnt pipeline ----------
// A-swizzle (row>>1)&3: 2-way bank aliasing on ds_read_b128 (free) vs 4-way with row&3.
// 1D grid 768: f -> xcd=f&7, l=f>>3; ytile=xcd*4+(l&3); zx=l>>2; z=zx>>3; xtile=zx&7.
// z==0 writes Q pre-scaled by SCL (folded out of attention's inner loop).
__global__ __launch_bounds__(256)
void gemm_qkv(const bf16_t* __restrict__ A,
              const bf16x8* __restrict__ Wp0, const bf16x8* __restrict__ Wp1,
              const bf16x8* __restrict__ Wp2,
              const float* __restrict__ b0, const float* __restrict__ b1,
              const float* __restrict__ b2,
              bf16_t* __restrict__ C0, bf16_t* __restrict__ C1,
              bf16_t* __restrict__ Vt) {
    // 48 KB: buf b at +b*16384 : A-tile 8KB (128r x 4 slots, swz) | B-tile 8KB [4][128]
    __shared__ bf16x8 smem_v[3072];
    char* const smem = (char*)smem_v;

    const int f = blockIdx.x;
    const int xcd = f & 7, l = f >> 3;       // l 0..95
    const int ytile = xcd * 4 + (l & 3);     // 0..31
    const int zx = l >> 2;                   // 0..23
    const int z = zx >> 3;                   // 0..2
    const int xtile = zx & 7;                // 0..7

    const bf16x8* Wp = (z == 0) ? Wp0 : (z == 1) ? Wp1 : Wp2;
    const float* bias = (z == 0) ? b0 : (z == 1) ? b1 : b2;

    const int tid = threadIdx.x;
    const int ln = tid & 63, wv = tid >> 6;
    const int quad = ln >> 4, l15 = ln & 15;
    const int wr = wv >> 1, wc = wv & 1;
    const int m0 = ytile * 128;
    const int n0 = xtile * 128;

    int arow[2], acl[2], bg[2], bn[2];
    #pragma unroll
    for (int u = 0; u < 2; ++u) {
        const int S = (wv * 2 + u) * 64 + ln;
        arow[u] = S >> 2; acl[u] = (S & 3) ^ ((arow[u] >> 1) & 3);
        bg[u] = S >> 7;   bn[u] = S & 127;
    }

    f32x4 acc[4][4];
    #pragma unroll
    for (int i = 0; i < 4; ++i)
        #pragma unroll
        for (int j = 0; j < 4; ++j) acc[i][j] = (f32x4){0.f, 0.f, 0.f, 0.f};

    auto stage = [&](int t, int buf) {       // t, buf literal at call sites
        char* const base = smem + buf * 16384;
        const int k0 = t * 32, kg0 = t * 4;
        #pragma unroll
        for (int u = 0; u < 2; ++u) {
            gload16(&A[(size_t)(m0 + arow[u]) * DD + k0 + acl[u] * 8],
                    base + (wv * 2 + u) * 1024);
            gload16(&Wp[(size_t)(kg0 + bg[u]) * DD + n0 + bn[u]],
                    base + 8192 + (wv * 2 + u) * 1024);
        }
    };

    // prologue: tiles 0,1 in flight; wait tile0 only
    stage(0, 0);
    stage(1, 1);
    asm volatile("s_waitcnt vmcnt(4)" ::: "memory");
    __builtin_amdgcn_s_barrier();

    #pragma unroll
    for (int t = 0; t < 32; ++t) {
        const int bsel = t % 3;              // literal after unroll
        const bf16x8 (*As)[4]   = reinterpret_cast<const bf16x8(*)[4]>(smem + bsel * 16384);
        const bf16x8 (*Bs)[128] = reinterpret_cast<const bf16x8(*)[128]>(smem + bsel * 16384 + 8192);
        bf16x8 fa[4], fb[4];
        #pragma unroll
        for (int mi = 0; mi < 4; ++mi) {
            const int row = wr * 64 + mi * 16 + l15;
            fa[mi] = As[row][quad ^ ((row >> 1) & 3)];
        }
        #pragma unroll
        for (int ni = 0; ni < 4; ++ni)
            fb[ni] = Bs[quad][wc * 64 + ni * 16 + l15];
        if (t + 2 < 32) stage(t + 2, (t + 2) % 3);   // stays in flight across barrier
        #pragma unroll
        for (int mi = 0; mi < 4; ++mi)
            #pragma unroll
            for (int ni = 0; ni < 4; ++ni)
                acc[mi][ni] = __builtin_amdgcn_mfma_f32_16x16x32_bf16(
                    fa[mi], fb[ni], acc[mi][ni], 0, 0, 0);
        // counted wait: only tile t+1 (oldest 4 loads) must be done
        if (t < 30)       asm volatile("s_waitcnt vmcnt(4)" ::: "memory");
        else if (t == 30) asm volatile("s_waitcnt vmcnt(0)" ::: "memory");
        if (t < 31) __builtin_amdgcn_s_barrier();
    }

    if (z < 2) {
        bf16_t* C = (z == 0) ? C0 : C1;
        const float sc = (z == 0) ? SCL : 1.0f;
        #pragma unroll
        for (int ni = 0; ni < 4; ++ni) {
            const int col = n0 + wc * 64 + ni * 16 + l15;
            const float bv = bias[col];
            #pragma unroll
            for (int mi = 0; mi < 4; ++mi)
                #pragma unroll
                for (int r = 0; r < 4; ++r) {
                    const int row = m0 + wr * 64 + mi * 16 + quad * 4 + r;
                    C[(size_t)row * DD + col] = f2bf((acc[mi][ni][r] + bv) * sc);
                }
        }
    } else {
        // V: LDS-bounce transpose, then coalesced Vt[bh][d][s] stores
        unsigned short (*T)[136] = reinterpret_cast<unsigned short(*)[136]>(smem);
        __syncthreads();   // all waves done reading LDS bufs before overwrite
        #pragma unroll
        for (int ni = 0; ni < 4; ++ni) {
            const int cl = wc * 64 + ni * 16 + l15;
            const float bv = bias[n0 + cl];
            #pragma unroll
            for (int mi = 0; mi < 4; ++mi) {
                const int rl = wr * 64 + mi * 16 + quad * 4;
                uint2 pk;
                pk.x = cvtpk(acc[mi][ni][0] + bv, acc[mi][ni][1] + bv);
                pk.y = cvtpk(acc[mi][ni][2] + bv, acc[mi][ni][3] + bv);
                *reinterpret_cast<uint2*>(&T[cl][rl]) = pk;
            }
        }
        __syncthreads();
        const int b = m0 >> 11, s0 = m0 & 2047, h0 = n0 >> 6;
        #pragma unroll
        for (int u = 0; u < 8; ++u) {
            const int c = u * 256 + tid;
            const int s8 = c & 15, nl = c >> 4;
            const bf16x8 v = *reinterpret_cast<const bf16x8*>(&T[nl][s8 * 8]);
            const int bh = b * 16 + h0 + (nl >> 6), d = nl & 63;
            *reinterpret_cast<bf16x8*>(
                &Vt[((size_t)bh * 64 + d) * SS + s0 + s8 * 8]) = v;
        }
    }
}

// ---------- output GEMM: 128x64 tile, BK=32, 3-buf counted-vmcnt pipeline ----------
// 1D grid 512: xcd=f&7, l=f>>3; ytile=xcd*4+(l&3); xtile=l>>2 (0..15).
__global__ __launch_bounds__(256)
void gemm_out(const bf16_t* __restrict__ A, const bf16x8* __restrict__ Wp,
              const float* __restrict__ bias, float* __restrict__ C) {
    // 36 KB: buf b at +b*12288 : A-tile 8KB | B-tile 4KB [4][64]
    __shared__ bf16x8 smem_v[2304];
    char* const smem = (char*)smem_v;

    const int f = blockIdx.x;
    const int xcd = f & 7, l = f >> 3;       // l 0..63
    const int ytile = xcd * 4 + (l & 3);     // 0..31
    const int xtile = l >> 2;                // 0..15

    const int tid = threadIdx.x;
    const int ln = tid & 63, wv = tid >> 6;
    const int quad = ln >> 4, l15 = ln & 15;
    const int wr = wv >> 1, wc = wv & 1;
    const int m0 = ytile * 128;
    const int n0 = xtile * 64;

    int arow[2], acl[2];
    #pragma unroll
    for (int u = 0; u < 2; ++u) {
        const int S = (wv * 2 + u) * 64 + ln;
        arow[u] = S >> 2; acl[u] = (S & 3) ^ ((arow[u] >> 1) & 3);
    }
    const int Sb = wv * 64 + ln;
    const int bkg = Sb >> 6, bnn = Sb & 63;

    f32x4 acc[4][2];
    #pragma unroll
    for (int i = 0; i < 4; ++i)
        #pragma unroll
        for (int j = 0; j < 2; ++j) acc[i][j] = (f32x4){0.f, 0.f, 0.f, 0.f};

    auto stage = [&](int t, int buf) {
        char* const base = smem + buf * 12288;
        const int k0 = t * 32, kg0 = t * 4;
        #pragma unroll
        for (int u = 0; u < 2; ++u)
            gload16(&A[(size_t)(m0 + arow[u]) * DD + k0 + acl[u] * 8],
                    base + (wv * 2 + u) * 1024);
        gload16(&Wp[(size_t)(kg0 + bkg) * DD + n0 + bnn],
                base + 8192 + wv * 1024);
    };

    stage(0, 0);
    stage(1, 1);
    asm volatile("s_waitcnt vmcnt(3)" ::: "memory");
    __builtin_amdgcn_s_barrier();

    #pragma unroll
    for (int t = 0; t < 32; ++t) {
        const int bsel = t % 3;
        const bf16x8 (*As)[4]  = reinterpret_cast<const bf16x8(*)[4]>(smem + bsel * 12288);
        const bf16x8 (*Bs)[64] = reinterpret_cast<const bf16x8(*)[64]>(smem + bsel * 12288 + 8192);
        bf16x8 fa[4], fb[2];
        #pragma unroll
        for (int mi = 0; mi < 4; ++mi) {
            const int row = wr * 64 + mi * 16 + l15;
            fa[mi] = As[row][quad ^ ((row >> 1) & 3)];
        }
        #pragma unroll
        for (int ni = 0; ni < 2; ++ni)
            fb[ni] = Bs[quad][wc * 32 + ni * 16 + l15];
        if (t + 2 < 32) stage(t + 2, (t + 2) % 3);
        #pragma unroll
        for (int mi = 0; mi < 4; ++mi)
            #pragma unroll
            for (int ni = 0; ni < 2; ++ni)
                acc[mi][ni] = __builtin_amdgcn_mfma_f32_16x16x32_bf16(
                    fa[mi], fb[ni], acc[mi][ni], 0, 0, 0);
        if (t < 30)       asm volatile("s_waitcnt vmcnt(3)" ::: "memory");
        else if (t == 30) asm volatile("s_waitcnt vmcnt(0)" ::: "memory");
        if (t < 31) __builtin_amdgcn_s_barrier();
    }

    #pragma unroll
    for (int ni = 0; ni < 2; ++ni) {
        const int col = n0 + wc * 32 + ni * 16 + l15;
        const float bv = bias[col];
        #pragma unroll
        for (int mi = 0; mi < 4; ++mi)
            #pragma unroll
            for (int r = 0; r < 4; ++r) {
                const int row = m0 + wr * 64 + mi * 16 + quad * 4 + r;
                C[(size_t)row * DD + col] = acc[mi][ni][r] + bv;
            }
    }
}

// ---------- MFMA flash attention: q-tile 64, K in LDS, V reg-prefetched 1 tile ahead ----------
// T14 issue-early/consume-late: V loads for tile t+1 issued before compute of tile t;
// barrier vmcnt(0) completes them. fv addressing verified correct in r10 (passed).
// Q pre-scaled by SCL; -FM folded into QK^T acc init.
// 1D grid 1024: xcd=f&7, l=f>>3; bh=xcd*4+(l&3); ytile=l>>2 (0..31).
__global__ __launch_bounds__(256)
void attn_mfma(const bf16_t* __restrict__ Q, const bf16_t* __restrict__ Kg,
               const bf16_t* __restrict__ Vt, bf16_t* __restrict__ Ctx) {
    __shared__ bf16x8 Ks[2][64][8];             // dbuf x 64 keys, swz c^(r&7): 16 KB
    __shared__ unsigned short Ps[4][16][64];    // per-wave P^T [q][key]: 8 KB
    // LDS = 24 KB

    const int tid = threadIdx.x;
    const int ln = tid & 63, w = tid >> 6;
    const int quad = ln >> 4, l15 = ln & 15;

    const int f = blockIdx.x;
    const int xcd = f & 7, l = f >> 3;       // l 0..127
    const int bh = xcd * 4 + (l & 3);        // 0..31
    const int ytile = l >> 2;                // 0..31
    const int tswz = (bh + ytile) & 15;
    const int qt = (ytile < 16) ? tswz : 31 - tswz;   // 0..31

    const int b = bh >> 4, h = bh & 15;
    const size_t rowbase = (size_t)b * SS;
    const int col0 = h * 64;

    const int krow0 = w * 16 + (ln >> 3);
    const int krow1 = krow0 + 8;
    const int kc0 = (ln & 7) ^ (krow0 & 7);
    const int kc1 = (ln & 7) ^ (krow1 & 7);

    bf16x8 fq[2];
    const int qrow = qt * 64 + w * 16 + l15;
    #pragma unroll
    for (int kk = 0; kk < 2; ++kk)
        fq[kk] = *reinterpret_cast<const bf16x8*>(
            &Q[(rowbase + qrow) * DD + col0 + kk * 32 + quad * 8]);

    f32x4 acc_o[4];
    #pragma unroll
    for (int i = 0; i < 4; ++i) acc_o[i] = (f32x4){0.f, 0.f, 0.f, 0.f};
    float lsum = 0.f;

    // running global pointers: K stage advances 64 keys/tile; V lane-ptr 64 cols/tile
    const bf16_t* kp0 = &Kg[(rowbase + krow0) * DD + col0 + kc0 * 8];
    const bf16_t* kp1 = &Kg[(rowbase + krow1) * DD + col0 + kc1 * 8];
    const bf16_t* vlane = &Vt[((size_t)bh * 64 + l15) * SS + quad * 8];

    auto stageadv = [&](int buf) {           // buf literal at call sites
        char* kb = (char*)Ks + buf * 8192 + w * 2048;
        gload16(kp0, kb);
        gload16(kp1, kb + 1024);
        kp0 += 64 * DD; kp1 += 64 * DD;      // next 64 keys
    };

    bf16x8 fvA[2][4], fvB[2][4];
    auto vload = [&](bf16x8 (&dst)[2][4]) {  // issue 8 b128 loads, advance to next tile
        #pragma unroll
        for (int kk = 0; kk < 2; ++kk)
            #pragma unroll
            for (int nd = 0; nd < 4; ++nd)
                dst[kk][nd] = *reinterpret_cast<const bf16x8*>(
                    vlane + (size_t)nd * 16 * SS + kk * 32);
        vlane += 64;
    };

    const int swz = l15 & 7;

    // buf literal at call sites; dq=112 literal -> mask code folds away
    auto compute_tile = [&](int buf, const bf16x8 (&fv)[2][4], int dq) {
        unsigned short* const psw = &Ps[w][l15][0];
        #pragma unroll
        for (int ni = 0; ni < 4; ++ni) {
            const int slot = ni * 4 + quad;
            unsigned short* pdst = psw + (((slot >> 1) ^ swz) * 8 + (slot & 1) * 4);
            const int g = ni * 16;
            if (g > dq) {
                *reinterpret_cast<uint2*>(pdst) = (uint2){0u, 0u};
                continue;
            }
            f32x4 st = (f32x4){-FM, -FM, -FM, -FM};   // -FM folded into acc init
            const int krow = ni * 16 + l15;
            #pragma unroll
            for (int kk = 0; kk < 2; ++kk) {
                const bf16x8 fk = Ks[buf][krow][(kk * 4 + quad) ^ (krow & 7)];
                st = __builtin_amdgcn_mfma_f32_16x16x32_bf16(fk, fq[kk], st, 0, 0, 0);
            }
            float p[4];
            #pragma unroll
            for (int r = 0; r < 4; ++r) {
                p[r] = __builtin_amdgcn_exp2f(st[r]);
                if (g == dq && (quad * 4 + r) > l15) p[r] = 0.f;
            }
            lsum += (p[0] + p[1]) + (p[2] + p[3]);
            uint2 pk;
            pk.x = cvtpk(p[0], p[1]);
            pk.y = cvtpk(p[2], p[3]);
            *reinterpret_cast<uint2*>(pdst) = pk;
        }
        // PV from registers (prefetched last tile)
        __builtin_amdgcn_s_setprio(1);
        #pragma unroll
        for (int kk = 0; kk < 2; ++kk) {
            const bf16x8 fp = *reinterpret_cast<const bf16x8*>(
                &Ps[w][l15][(((kk * 4 + quad) ^ swz) * 8)]);
            #pragma unroll
            for (int nd = 0; nd < 4; ++nd)
                acc_o[nd] = __builtin_amdgcn_mfma_f32_16x16x32_bf16(fv[kk][nd], fp, acc_o[nd], 0, 0, 0);
        }
        __builtin_amdgcn_s_setprio(0);
    };

    // pipeline: literal bufs + named V reg-sets, pairwise unrolled
    stageadv(0);                 // K tile0 -> buf0
    vload(fvA);                  // V tile0 -> regs A
    __syncthreads();             // vmcnt(0): K0 in LDS, V0 in regs
    int t = 0;
    while (t + 2 <= qt) {
        stageadv(1);             // K t+1 -> buf1
        vload(fvB);              // V t+1 -> regs B (completes at barrier)
        compute_tile(0, fvA, 112);
        __syncthreads();
        stageadv(0);             // K t+2 -> buf0
        vload(fvA);              // V t+2 -> regs A
        compute_tile(1, fvB, 112);
        __syncthreads();
        t += 2;
    }
    if (t < qt) {                // t == qt-1: full tile in buf0/fvA; diag -> buf1/fvB
        stageadv(1);
        vload(fvB);
        compute_tile(0, fvA, 112);
        __syncthreads();
        compute_tile(1, fvB, w * 16);
    } else {                     // t == qt: diag tile in buf0/fvA
        compute_tile(0, fvA, w * 16);
    }

    {
        float s = lsum;
        s += __shfl_xor(s, 16);
        s += __shfl_xor(s, 32);
        const float inv = 1.f / s;
        const size_t orow = (rowbase + qrow) * DD + col0;
        #pragma unroll
        for (int nd = 0; nd < 4; ++nd) {
            uint2 ov;
            ov.x = cvtpk(acc_o[nd][0] * inv, acc_o[nd][1] * inv);
            ov.y = cvtpk(acc_o[nd][2] * inv, acc_o[nd][3] * inv);
            *reinterpret_cast<uint2*>(&Ctx[orow + nd * 16 + quad * 4]) = ov;
        }
    }
}

extern "C" void kernel_launch(void* const* d_in, const int* in_sizes, int n_in,
                              void* d_out, int out_size, void* d_ws, size_t ws_size,
                              hipStream_t stream) {
    const float* x  = (const float*)d_in[0];
    const float* Wq = (const float*)d_in[1];
    const float* bq = (const float*)d_in[2];
    const float* Wk = (const float*)d_in[3];
    const float* bk = (const float*)d_in[4];
    const float* Wv = (const float*)d_in[5];
    const float* bv = (const float*)d_in[6];
    const float* Wo = (const float*)d_in[7];
    const float* bo = (const float*)d_in[8];
    float* out = (float*)d_out;

    const size_t M = (size_t)BB * SS;        // 4096
    const size_t mat = M * DD;               // 4M elements
    const size_t wsz = (size_t)DD * DD;

    bf16_t* ws = (bf16_t*)d_ws;
    bf16_t* xb   = ws;                       // 4M
    bf16_t* Wqp  = ws + mat;                 // 1M each
    bf16_t* Wkp  = Wqp + wsz;
    bf16_t* Wvp  = Wkp + wsz;
    bf16_t* Wop  = Wvp + wsz;
    bf16_t* Qb   = Wop + wsz;                // 4M
    bf16_t* Kb   = Qb + mat;                 // 4M
    bf16_t* Vtb  = Kb + mat;                 // 4M
    bf16_t* Ctxb = Vtb + mat;                // 4M -> 48 MB total

    dim3 blk(256);
    hipLaunchKernelGGL(prep_kernel, dim3(2560), blk, 0, stream,
                       x, xb, Wq, Wk, Wv, Wo,
                       (bf16x8*)Wqp, (bf16x8*)Wkp, (bf16x8*)Wvp, (bf16x8*)Wop);

    hipLaunchKernelGGL(gemm_qkv, dim3(768), blk, 0, stream,
                       xb, (const bf16x8*)Wqp, (const bf16x8*)Wkp, (const bf16x8*)Wvp,
                       bq, bk, bv, Qb, Kb, Vtb);

    hipLaunchKernelGGL(attn_mfma, dim3(1024), blk, 0, stream,
                       Qb, Kb, Vtb, Ctxb);

    hipLaunchKernelGGL(gemm_out, dim3(512), blk, 0, stream,
                       Ctxb, (const bf16x8*)Wop, bo, out);
}

// Round 13
// 167.858 us; speedup vs baseline: 1.3287x; 1.3287x over previous
//
#include <hip/hip_runtime.h>
#include <math.h>

#define BB 2
#define SS 2048
#define DD 1024
#define HH 16
#define HDIM 64

typedef __bf16 bf16_t;
typedef __attribute__((ext_vector_type(8))) __bf16 bf16x8;
typedef __attribute__((ext_vector_type(4))) __bf16 bf16x4;
typedef __attribute__((ext_vector_type(4))) float f32x4;

__device__ inline bf16_t f2bf(float f) {
    unsigned int x; __builtin_memcpy(&x, &f, 4);
    unsigned int r = (x + 0x7FFFu + ((x >> 16) & 1u)) >> 16;  // RNE
    unsigned short us = (unsigned short)r;
    bf16_t b; __builtin_memcpy(&b, &us, 2); return b;
}
__device__ inline unsigned int cvtpk(float a, float b) {  // lo=bf16(a), hi=bf16(b), RNE
    unsigned int r;
    asm("v_cvt_pk_bf16_f32 %0, %1, %2" : "=v"(r) : "v"(a), "v"(b));
    return r;
}
__device__ inline void gload16(const void* g, void* lds_base) {
    __builtin_amdgcn_global_load_lds(
        (const __attribute__((address_space(1))) void*)g,
        (__attribute__((address_space(3))) void*)lds_base, 16, 0, 0);
}

#define SCL 0.18033688f   // (1/sqrt(64)) * log2(e)
#define FM  12.0f

// ---------- prep: dense grid; blocks 0..2047 x-cvt, 2048..2559 pack 4 weights ----------
__global__ __launch_bounds__(256)
void prep_kernel(const float* __restrict__ x, bf16_t* __restrict__ xb,
                 const float* __restrict__ W0, const float* __restrict__ W1,
                 const float* __restrict__ W2, const float* __restrict__ W3,
                 bf16x8* __restrict__ P0, bf16x8* __restrict__ P1,
                 bf16x8* __restrict__ P2, bf16x8* __restrict__ P3) {
    const int bid = blockIdx.x, tid = threadIdx.x;
    if (bid < 2048) {
        const int i = bid * 512 + tid;
        #pragma unroll
        for (int u = 0; u < 2; ++u) {
            const int j = i + u * 256;
            const float4 v = reinterpret_cast<const float4*>(x)[j];
            bf16x4 o;
            o.x = f2bf(v.x); o.y = f2bf(v.y); o.z = f2bf(v.z); o.w = f2bf(v.w);
            reinterpret_cast<bf16x4*>(xb)[j] = o;
        }
    } else {
        const int t = (bid - 2048) * 256 + tid;   // 0..131071
        const int g = t >> 10, n = t & 1023;
        const float* Ws[4] = {W0, W1, W2, W3};
        bf16x8* Pp[4] = {P0, P1, P2, P3};
        #pragma unroll
        for (int m = 0; m < 4; ++m) {
            bf16x8 v;
            #pragma unroll
            for (int j = 0; j < 8; ++j) v[j] = f2bf(Ws[m][(size_t)(g * 8 + j) * DD + n]);
            Pp[m][(size_t)g * DD + n] = v;
        }
    }
}

// ---------- fused QKV GEMM: 128x128 tile, BK=32, 3-buf counted-vmcnt pipeline ----------
// A-swizzle (row>>1)&3: 2-way bank aliasing on ds_read_b128 (free) vs 4-way with row&3.
// 1D grid 768: f -> xcd=f&7, l=f>>3; ytile=xcd*4+(l&3); zx=l>>2; z=zx>>3; xtile=zx&7.
// z==0 writes Q pre-scaled by SCL (folded out of attention's inner loop).
__global__ __launch_bounds__(256)
void gemm_qkv(const bf16_t* __restrict__ A,
              const bf16x8* __restrict__ Wp0, const bf16x8* __restrict__ Wp1,
              const bf16x8* __restrict__ Wp2,
              const float* __restrict__ b0, const float* __restrict__ b1,
              const float* __restrict__ b2,
              bf16_t* __restrict__ C0, bf16_t* __restrict__ C1,
              bf16_t* __restrict__ Vt) {
    // 48 KB: buf b at +b*16384 : A-tile 8KB (128r x 4 slots, swz) | B-tile 8KB [4][128]
    __shared__ bf16x8 smem_v[3072];
    char* const smem = (char*)smem_v;

    const int f = blockIdx.x;
    const int xcd = f & 7, l = f >> 3;       // l 0..95
    const int ytile = xcd * 4 + (l & 3);     // 0..31
    const int zx = l >> 2;                   // 0..23
    const int z = zx >> 3;                   // 0..2
    const int xtile = zx & 7;                // 0..7

    const bf16x8* Wp = (z == 0) ? Wp0 : (z == 1) ? Wp1 : Wp2;
    const float* bias = (z == 0) ? b0 : (z == 1) ? b1 : b2;

    const int tid = threadIdx.x;
    const int ln = tid & 63, wv = tid >> 6;
    const int quad = ln >> 4, l15 = ln & 15;
    const int wr = wv >> 1, wc = wv & 1;
    const int m0 = ytile * 128;
    const int n0 = xtile * 128;

    int arow[2], acl[2], bg[2], bn[2];
    #pragma unroll
    for (int u = 0; u < 2; ++u) {
        const int S = (wv * 2 + u) * 64 + ln;
        arow[u] = S >> 2; acl[u] = (S & 3) ^ ((arow[u] >> 1) & 3);
        bg[u] = S >> 7;   bn[u] = S & 127;
    }

    f32x4 acc[4][4];
    #pragma unroll
    for (int i = 0; i < 4; ++i)
        #pragma unroll
        for (int j = 0; j < 4; ++j) acc[i][j] = (f32x4){0.f, 0.f, 0.f, 0.f};

    auto stage = [&](int t, int buf) {       // t, buf literal at call sites
        char* const base = smem + buf * 16384;
        const int k0 = t * 32, kg0 = t * 4;
        #pragma unroll
        for (int u = 0; u < 2; ++u) {
            gload16(&A[(size_t)(m0 + arow[u]) * DD + k0 + acl[u] * 8],
                    base + (wv * 2 + u) * 1024);
            gload16(&Wp[(size_t)(kg0 + bg[u]) * DD + n0 + bn[u]],
                    base + 8192 + (wv * 2 + u) * 1024);
        }
    };

    // prologue: tiles 0,1 in flight; wait tile0 only
    stage(0, 0);
    stage(1, 1);
    asm volatile("s_waitcnt vmcnt(4)" ::: "memory");
    __builtin_amdgcn_s_barrier();

    #pragma unroll
    for (int t = 0; t < 32; ++t) {
        const int bsel = t % 3;              // literal after unroll
        const bf16x8 (*As)[4]   = reinterpret_cast<const bf16x8(*)[4]>(smem + bsel * 16384);
        const bf16x8 (*Bs)[128] = reinterpret_cast<const bf16x8(*)[128]>(smem + bsel * 16384 + 8192);
        bf16x8 fa[4], fb[4];
        #pragma unroll
        for (int mi = 0; mi < 4; ++mi) {
            const int row = wr * 64 + mi * 16 + l15;
            fa[mi] = As[row][quad ^ ((row >> 1) & 3)];
        }
        #pragma unroll
        for (int ni = 0; ni < 4; ++ni)
            fb[ni] = Bs[quad][wc * 64 + ni * 16 + l15];
        if (t + 2 < 32) stage(t + 2, (t + 2) % 3);   // stays in flight across barrier
        #pragma unroll
        for (int mi = 0; mi < 4; ++mi)
            #pragma unroll
            for (int ni = 0; ni < 4; ++ni)
                acc[mi][ni] = __builtin_amdgcn_mfma_f32_16x16x32_bf16(
                    fa[mi], fb[ni], acc[mi][ni], 0, 0, 0);
        // counted wait: only tile t+1 (oldest 4 loads) must be done
        if (t < 30)       asm volatile("s_waitcnt vmcnt(4)" ::: "memory");
        else if (t == 30) asm volatile("s_waitcnt vmcnt(0)" ::: "memory");
        if (t < 31) __builtin_amdgcn_s_barrier();
    }

    if (z < 2) {
        bf16_t* C = (z == 0) ? C0 : C1;
        const float sc = (z == 0) ? SCL : 1.0f;
        #pragma unroll
        for (int ni = 0; ni < 4; ++ni) {
            const int col = n0 + wc * 64 + ni * 16 + l15;
            const float bv = bias[col];
            #pragma unroll
            for (int mi = 0; mi < 4; ++mi)
                #pragma unroll
                for (int r = 0; r < 4; ++r) {
                    const int row = m0 + wr * 64 + mi * 16 + quad * 4 + r;
                    C[(size_t)row * DD + col] = f2bf((acc[mi][ni][r] + bv) * sc);
                }
        }
    } else {
        // V: LDS-bounce transpose, then coalesced Vt[bh][d][s] stores
        unsigned short (*T)[136] = reinterpret_cast<unsigned short(*)[136]>(smem);
        __syncthreads();   // all waves done reading LDS bufs before overwrite
        #pragma unroll
        for (int ni = 0; ni < 4; ++ni) {
            const int cl = wc * 64 + ni * 16 + l15;
            const float bv = bias[n0 + cl];
            #pragma unroll
            for (int mi = 0; mi < 4; ++mi) {
                const int rl = wr * 64 + mi * 16 + quad * 4;
                uint2 pk;
                pk.x = cvtpk(acc[mi][ni][0] + bv, acc[mi][ni][1] + bv);
                pk.y = cvtpk(acc[mi][ni][2] + bv, acc[mi][ni][3] + bv);
                *reinterpret_cast<uint2*>(&T[cl][rl]) = pk;
            }
        }
        __syncthreads();
        const int b = m0 >> 11, s0 = m0 & 2047, h0 = n0 >> 6;
        #pragma unroll
        for (int u = 0; u < 8; ++u) {
            const int c = u * 256 + tid;
            const int s8 = c & 15, nl = c >> 4;
            const bf16x8 v = *reinterpret_cast<const bf16x8*>(&T[nl][s8 * 8]);
            const int bh = b * 16 + h0 + (nl >> 6), d = nl & 63;
            *reinterpret_cast<bf16x8*>(
                &Vt[((size_t)bh * 64 + d) * SS + s0 + s8 * 8]) = v;
        }
    }
}

// ---------- output GEMM: 128x64 tile, BK=64, 3-buf counted-vmcnt (16 steps) ----------
// Half the barrier/drain events vs BK=32. A-tile 8-slot swz (row&7): 2-way, free.
// 1D grid 512: xcd=f&7, l=f>>3; ytile=xcd*4+(l&3); xtile=l>>2 (0..15).
__global__ __launch_bounds__(256)
void gemm_out(const bf16_t* __restrict__ A, const bf16x8* __restrict__ Wp,
              const float* __restrict__ bias, float* __restrict__ C) {
    // 72 KB: buf b at +b*24576 : A-tile 16KB [128r][8 slots, swz] | B-tile 8KB [8][64]
    __shared__ bf16x8 smem_v[4608];
    char* const smem = (char*)smem_v;

    const int f = blockIdx.x;
    const int xcd = f & 7, l = f >> 3;       // l 0..63
    const int ytile = xcd * 4 + (l & 3);     // 0..31
    const int xtile = l >> 2;                // 0..15

    const int tid = threadIdx.x;
    const int ln = tid & 63, wv = tid >> 6;
    const int quad = ln >> 4, l15 = ln & 15;
    const int wr = wv >> 1, wc = wv & 1;
    const int m0 = ytile * 128;
    const int n0 = xtile * 64;

    int arow[4], acl[4], bkg[2], bnn[2];
    #pragma unroll
    for (int u = 0; u < 4; ++u) {
        const int S = (wv * 4 + u) * 64 + ln;        // 0..1023
        arow[u] = S >> 3; acl[u] = (S & 7) ^ (arow[u] & 7);
    }
    #pragma unroll
    for (int u = 0; u < 2; ++u) {
        const int S = (wv * 2 + u) * 64 + ln;        // 0..511
        bkg[u] = S >> 6; bnn[u] = S & 63;
    }

    f32x4 acc[4][2];
    #pragma unroll
    for (int i = 0; i < 4; ++i)
        #pragma unroll
        for (int j = 0; j < 2; ++j) acc[i][j] = (f32x4){0.f, 0.f, 0.f, 0.f};

    auto stage = [&](int t, int buf) {       // t, buf literal at call sites
        char* const base = smem + buf * 24576;
        const int k0 = t * 64, kg0 = t * 8;
        #pragma unroll
        for (int u = 0; u < 4; ++u)
            gload16(&A[(size_t)(m0 + arow[u]) * DD + k0 + acl[u] * 8],
                    base + (wv * 4 + u) * 1024);
        #pragma unroll
        for (int u = 0; u < 2; ++u)
            gload16(&Wp[(size_t)(kg0 + bkg[u]) * DD + n0 + bnn[u]],
                    base + 16384 + (wv * 2 + u) * 1024);
    };

    // prologue: tiles 0,1 in flight (6 loads each); wait tile0 only
    stage(0, 0);
    stage(1, 1);
    asm volatile("s_waitcnt vmcnt(6)" ::: "memory");
    __builtin_amdgcn_s_barrier();

    #pragma unroll
    for (int t = 0; t < 16; ++t) {
        const int bsel = t % 3;
        const bf16x8 (*As)[8] = reinterpret_cast<const bf16x8(*)[8]>(smem + bsel * 24576);
        const bf16x8 (*Bs)[64] = reinterpret_cast<const bf16x8(*)[64]>(smem + bsel * 24576 + 16384);
        bf16x8 fa[2][4], fb[2][2];
        #pragma unroll
        for (int kk = 0; kk < 2; ++kk) {
            #pragma unroll
            for (int mi = 0; mi < 4; ++mi) {
                const int row = wr * 64 + mi * 16 + l15;
                fa[kk][mi] = As[row][(kk * 4 + quad) ^ (row & 7)];
            }
            #pragma unroll
            for (int ni = 0; ni < 2; ++ni)
                fb[kk][ni] = Bs[kk * 4 + quad][wc * 32 + ni * 16 + l15];
        }
        if (t + 2 < 16) stage(t + 2, (t + 2) % 3);
        #pragma unroll
        for (int kk = 0; kk < 2; ++kk)
            #pragma unroll
            for (int mi = 0; mi < 4; ++mi)
                #pragma unroll
                for (int ni = 0; ni < 2; ++ni)
                    acc[mi][ni] = __builtin_amdgcn_mfma_f32_16x16x32_bf16(
                        fa[kk][mi], fb[kk][ni], acc[mi][ni], 0, 0, 0);
        if (t < 14)       asm volatile("s_waitcnt vmcnt(6)" ::: "memory");
        else if (t == 14) asm volatile("s_waitcnt vmcnt(0)" ::: "memory");
        if (t < 15) __builtin_amdgcn_s_barrier();
    }

    #pragma unroll
    for (int ni = 0; ni < 2; ++ni) {
        const int col = n0 + wc * 32 + ni * 16 + l15;
        const float bv = bias[col];
        #pragma unroll
        for (int mi = 0; mi < 4; ++mi)
            #pragma unroll
            for (int r = 0; r < 4; ++r) {
                const int row = m0 + wr * 64 + mi * 16 + quad * 4 + r;
                C[(size_t)row * DD + col] = acc[mi][ni][r] + bv;
            }
    }
}

// ---------- MFMA flash attention: q-tile 64, 1024 blocks (4/CU), literal-buf pipeline ----------
// (exact r6/r9-passing version) Q pre-scaled by SCL; -FM folded into QK^T acc init.
// 1D grid 1024: xcd=f&7, l=f>>3; bh=xcd*4+(l&3); ytile=l>>2 (0..31).
__global__ __launch_bounds__(256)
void attn_mfma(const bf16_t* __restrict__ Q, const bf16_t* __restrict__ Kg,
               const bf16_t* __restrict__ Vt, bf16_t* __restrict__ Ctx) {
    __shared__ bf16x8 Ks[2][64][8];             // dbuf x 64 keys, swz c^(r&7): 16 KB
    __shared__ bf16x8 Vs[2][64][8];             // dbuf x 64 d-rows: 16 KB
    __shared__ unsigned short Ps[4][16][64];    // per-wave P^T [q][key]: 8 KB
    // LDS = 40 KB -> 4 blocks/CU

    const int tid = threadIdx.x;
    const int ln = tid & 63, w = tid >> 6;
    const int quad = ln >> 4, l15 = ln & 15;

    const int f = blockIdx.x;
    const int xcd = f & 7, l = f >> 3;       // l 0..127
    const int bh = xcd * 4 + (l & 3);        // 0..31
    const int ytile = l >> 2;                // 0..31
    const int tswz = (bh + ytile) & 15;
    const int qt = (ytile < 16) ? tswz : 31 - tswz;   // 0..31

    const int b = bh >> 4, h = bh & 15;
    const size_t rowbase = (size_t)b * SS;
    const int col0 = h * 64;

    const int krow0 = w * 16 + (ln >> 3);
    const int krow1 = krow0 + 8;
    const int kc0 = (ln & 7) ^ (krow0 & 7);
    const int kc1 = (ln & 7) ^ (krow1 & 7);

    bf16x8 fq[2];
    const int qrow = qt * 64 + w * 16 + l15;
    #pragma unroll
    for (int kk = 0; kk < 2; ++kk)
        fq[kk] = *reinterpret_cast<const bf16x8*>(
            &Q[(rowbase + qrow) * DD + col0 + kk * 32 + quad * 8]);

    f32x4 acc_o[4];
    #pragma unroll
    for (int i = 0; i < 4; ++i) acc_o[i] = (f32x4){0.f, 0.f, 0.f, 0.f};
    float lsum = 0.f;

    // running global pointers: constant-stride advance per staged tile
    const bf16_t* kp0 = &Kg[(rowbase + krow0) * DD + col0 + kc0 * 8];
    const bf16_t* kp1 = &Kg[(rowbase + krow1) * DD + col0 + kc1 * 8];
    const bf16_t* vp0 = &Vt[((size_t)bh * 64 + krow0) * SS + kc0 * 8];
    const bf16_t* vp1 = &Vt[((size_t)bh * 64 + krow1) * SS + kc1 * 8];

    auto stageadv = [&](int buf) {           // buf literal at call sites
        char* kb = (char*)Ks + buf * 8192 + w * 2048;
        char* vb = (char*)Vs + buf * 8192 + w * 2048;
        gload16(kp0, kb);
        gload16(kp1, kb + 1024);
        gload16(vp0, vb);
        gload16(vp1, vb + 1024);
        kp0 += 64 * DD; kp1 += 64 * DD;      // next 64 keys
        vp0 += 64;      vp1 += 64;           // next 64 s-columns
    };

    const int swz = l15 & 7;

    // buf literal at call sites; dq=112 literal -> mask code folds away
    auto compute_tile = [&](int buf, int dq) {
        unsigned short* const psw = &Ps[w][l15][0];
        #pragma unroll
        for (int ni = 0; ni < 4; ++ni) {
            const int slot = ni * 4 + quad;
            unsigned short* pdst = psw + (((slot >> 1) ^ swz) * 8 + (slot & 1) * 4);
            const int g = ni * 16;
            if (g > dq) {
                *reinterpret_cast<uint2*>(pdst) = (uint2){0u, 0u};
                continue;
            }
            f32x4 st = (f32x4){-FM, -FM, -FM, -FM};   // -FM folded into acc init
            const int krow = ni * 16 + l15;
            #pragma unroll
            for (int kk = 0; kk < 2; ++kk) {
                const bf16x8 fk = Ks[buf][krow][(kk * 4 + quad) ^ (krow & 7)];
                st = __builtin_amdgcn_mfma_f32_16x16x32_bf16(fk, fq[kk], st, 0, 0, 0);
            }
            float p[4];
            #pragma unroll
            for (int r = 0; r < 4; ++r) {
                p[r] = __builtin_amdgcn_exp2f(st[r]);
                if (g == dq && (quad * 4 + r) > l15) p[r] = 0.f;
            }
            lsum += (p[0] + p[1]) + (p[2] + p[3]);
            uint2 pk;
            pk.x = cvtpk(p[0], p[1]);
            pk.y = cvtpk(p[2], p[3]);
            *reinterpret_cast<uint2*>(pdst) = pk;
        }
        // PV (setprio: favor MFMA waves while others stage/VALU)
        __builtin_amdgcn_s_setprio(1);
        #pragma unroll
        for (int kk = 0; kk < 2; ++kk) {
            const bf16x8 fp = *reinterpret_cast<const bf16x8*>(
                &Ps[w][l15][(((kk * 4 + quad) ^ swz) * 8)]);
            #pragma unroll
            for (int nd = 0; nd < 4; ++nd) {
                const int vrow = nd * 16 + l15;
                const bf16x8 fv = Vs[buf][vrow][(kk * 4 + quad) ^ (vrow & 7)];
                acc_o[nd] = __builtin_amdgcn_mfma_f32_16x16x32_bf16(fv, fp, acc_o[nd], 0, 0, 0);
            }
        }
        __builtin_amdgcn_s_setprio(0);
    };

    // pipeline: literal bufs, pairwise unrolled
    stageadv(0);                 // tile 0 -> buf0
    __syncthreads();
    int t = 0;
    while (t + 2 <= qt) {
        stageadv(1);             // tile t+1 -> buf1
        compute_tile(0, 112);
        __syncthreads();
        stageadv(0);             // tile t+2 -> buf0
        compute_tile(1, 112);
        __syncthreads();
        t += 2;
    }
    if (t < qt) {                // t == qt-1: one full tile left in buf0
        stageadv(1);             // tile qt (diag) -> buf1
        compute_tile(0, 112);
        __syncthreads();
        compute_tile(1, w * 16);
    } else {                     // t == qt: diag tile in buf0
        compute_tile(0, w * 16);
    }

    {
        float s = lsum;
        s += __shfl_xor(s, 16);
        s += __shfl_xor(s, 32);
        const float inv = 1.f / s;
        const size_t orow = (rowbase + qrow) * DD + col0;
        #pragma unroll
        for (int nd = 0; nd < 4; ++nd) {
            uint2 ov;
            ov.x = cvtpk(acc_o[nd][0] * inv, acc_o[nd][1] * inv);
            ov.y = cvtpk(acc_o[nd][2] * inv, acc_o[nd][3] * inv);
            *reinterpret_cast<uint2*>(&Ctx[orow + nd * 16 + quad * 4]) = ov;
        }
    }
}

extern "C" void kernel_launch(void* const* d_in, const int* in_sizes, int n_in,
                              void* d_out, int out_size, void* d_ws, size_t ws_size,
                              hipStream_t stream) {
    const float* x  = (const float*)d_in[0];
    const float* Wq = (const float*)d_in[1];
    const float* bq = (const float*)d_in[2];
    const float* Wk = (const float*)d_in[3];
    const float* bk = (const float*)d_in[4];
    const float* Wv = (const float*)d_in[5];
    const float* bv = (const float*)d_in[6];
    const float* Wo = (const float*)d_in[7];
    const float* bo = (const float*)d_in[8];
    float* out = (float*)d_out;

    const size_t M = (size_t)BB * SS;        // 4096
    const size_t mat = M * DD;               // 4M elements
    const size_t wsz = (size_t)DD * DD;

    bf16_t* ws = (bf16_t*)d_ws;
    bf16_t* xb   = ws;                       // 4M
    bf16_t* Wqp  = ws + mat;                 // 1M each
    bf16_t* Wkp  = Wqp + wsz;
    bf16_t* Wvp  = Wkp + wsz;
    bf16_t* Wop  = Wvp + wsz;
    bf16_t* Qb   = Wop + wsz;                // 4M
    bf16_t* Kb   = Qb + mat;                 // 4M
    bf16_t* Vtb  = Kb + mat;                 // 4M
    bf16_t* Ctxb = Vtb + mat;                // 4M -> 48 MB total

    dim3 blk(256);
    hipLaunchKernelGGL(prep_kernel, dim3(2560), blk, 0, stream,
                       x, xb, Wq, Wk, Wv, Wo,
                       (bf16x8*)Wqp, (bf16x8*)Wkp, (bf16x8*)Wvp, (bf16x8*)Wop);

    hipLaunchKernelGGL(gemm_qkv, dim3(768), blk, 0, stream,
                       xb, (const bf16x8*)Wqp, (const bf16x8*)Wkp, (const bf16x8*)Wvp,
                       bq, bk, bv, Qb, Kb, Vtb);

    hipLaunchKernelGGL(attn_mfma, dim3(1024), blk, 0, stream,
                       Qb, Kb, Vtb, Ctxb);

    hipLaunchKernelGGL(gemm_out, dim3(512), blk, 0, stream,
                       Ctxb, (const bf16x8*)Wop, bo, out);
}